// Round 7
// baseline (317.000 us; speedup 1.0000x reference)
//
#include <hip/hip_runtime.h>
#include <hip/hip_cooperative_groups.h>

namespace cg = cooperative_groups;

#define NN 100000
#define NE 3200000
#define NQ (NE / 4)            // 800000 int4 quads

// ---- bucketed-scatter plan constants ----
#define NCHUNK 32
#define CHUNK 3125             // 32 * 3125 = 100000 exactly; 12.5 KB LDS
#define NBB 512                // blocks (bucket ranges AND scatter tiles)
#define BCAP 320               // per-(chunk,block) capacity: mean 195 + 9 sigma
#define NSLICE 16              // scatter slices
#define GPS (NBB / NSLICE)     // segments per scatter slice = 32

// --------------------------------------------------------------------------
// Scatter phase (device fn): block (s,c) drains 32 segments (2 per wave)
// into the 12.5 KB LDS chunk accumulator, then writes one dense partial.
__device__ __forceinline__ void scatter_phase(
        const float* __restrict__ h,
        const unsigned* __restrict__ bkt, const int* __restrict__ counts,
        float* __restrict__ partial, float* acc) {
    const int s = blockIdx.x & (NSLICE - 1);
    const int c = blockIdx.x >> 4;
    for (int i = threadIdx.x; i < CHUNK; i += 1024) acc[i] = 0.0f;
    __syncthreads();
    const int lane = threadIdx.x & 63;
    const int w = threadIdx.x >> 6;
#pragma unroll
    for (int k = 0; k < 2; ++k) {
        const int b = s * GPS + w + k * 16;
        const int n = counts[c * NBB + b];
        const unsigned* bp = bkt + ((size_t)c * NBB + b) * BCAP;
        const uint4* bp4 = (const uint4*)bp;
        const int n4 = n >> 2;
        for (int q = lane; q < n4; q += 64) {
            const uint4 e = bp4[q];
            atomicAdd(&acc[e.x >> 17], h[e.x & 0x1FFFF]);
            atomicAdd(&acc[e.y >> 17], h[e.y & 0x1FFFF]);
            atomicAdd(&acc[e.z >> 17], h[e.z & 0x1FFFF]);
            atomicAdd(&acc[e.w >> 17], h[e.w & 0x1FFFF]);
        }
        const int base = n4 << 2;
        if (base + lane < n) {
            const unsigned e = bp[base + lane];
            atomicAdd(&acc[e >> 17], h[e & 0x1FFFF]);
        }
    }
    __syncthreads();
    float* outp = partial + ((size_t)c * NSLICE + s) * CHUNK;
    for (int i = threadIdx.x; i < CHUNK; i += 1024) outp[i] = acc[i];
}

// --------------------------------------------------------------------------
// Fused cooperative kernel: bucket -> scatter1 -> reduce+MLP -> scatter2
// -> reduce+final, with grid.sync() between phases. One dispatch.
__global__ __launch_bounds__(1024, 8) void fused_kernel(
        const float* __restrict__ features,
        const int4* __restrict__ src4, const int4* __restrict__ dst4,
        const float* __restrict__ W1, const float* __restrict__ b1,
        const float* __restrict__ W2, const float* __restrict__ b2,
        unsigned* __restrict__ bkt, int* __restrict__ counts,
        float* __restrict__ partial, float* __restrict__ sbuf,
        float* __restrict__ out) {
    cg::grid_group grid = cg::this_grid();
    __shared__ float acc[CHUNK];
    __shared__ int cnt[NCHUNK];

    // ---- Phase A: bucket edges by dst-chunk (LDS counters give slots) ----
    if (threadIdx.x < NCHUNK) cnt[threadIdx.x] = 0;
    __syncthreads();
    {
        const int b = blockIdx.x;
        const int q0 = (int)(((long long)b * NQ) / NBB);
        const int q1 = (int)(((long long)(b + 1) * NQ) / NBB);
        for (int q = q0 + threadIdx.x; q < q1; q += 1024) {
            const int4 d = dst4[q];
            const int4 s = src4[q];
            const int dd[4] = {d.x, d.y, d.z, d.w};
            const int ss[4] = {s.x, s.y, s.z, s.w};
#pragma unroll
            for (int j = 0; j < 4; ++j) {
                const int c = dd[j] / CHUNK;              // magic-mul div
                const int slot = atomicAdd(&cnt[c], 1);
                bkt[((size_t)c * NBB + b) * BCAP + slot] =
                    ((unsigned)(dd[j] - c * CHUNK) << 17) | (unsigned)ss[j];
            }
        }
        __syncthreads();
        if (threadIdx.x < NCHUNK)
            counts[threadIdx.x * NBB + b] = cnt[threadIdx.x];
    }
    grid.sync();

    // ---- Phase B: layer-1 scatter (gather features) ----
    scatter_phase(features, bkt, counts, partial, acc);
    grid.sync();

    // ---- Phase C: reduce 16 partials + collapsed 16-wide MLP -> sbuf ----
    {
        const int i = blockIdx.x * 1024 + threadIdx.x;
        if (i < NN) {
            const int c = i / CHUNK;
            const int idx = i - c * CHUNK;
            const float* base = partial + (size_t)c * NSLICE * CHUNK + idx;
            float a = 0.0f;
#pragma unroll
            for (int s = 0; s < NSLICE; ++s) a += base[(size_t)s * CHUNK];
            float r = 0.0f;
#pragma unroll
            for (int j = 0; j < 16; ++j)
                r = fmaf(fmaxf(fmaf(a, W1[j], b1[j]), 0.0f), W2[j], r);
            sbuf[i] = r;
        }
    }
    grid.sync();

    // ---- Phase D: layer-2 scatter (gather sbuf) ----
    scatter_phase(sbuf, bkt, counts, partial, acc);
    grid.sync();

    // ---- Phase E: reduce 16 partials + bias + relu -> out ----
    {
        const int i = blockIdx.x * 1024 + threadIdx.x;
        if (i < NN) {
            const int c = i / CHUNK;
            const int idx = i - c * CHUNK;
            const float* base = partial + (size_t)c * NSLICE * CHUNK + idx;
            float a = 0.0f;
#pragma unroll
            for (int s = 0; s < NSLICE; ++s) a += base[(size_t)s * CHUNK];
            out[i] = fmaxf(a + b2[0], 0.0f);
        }
    }
}

// ---------------- Fallback: R6 5-kernel path --------------------------------
__global__ __launch_bounds__(1024) void bucket_kernel(
        const int4* __restrict__ src4, const int4* __restrict__ dst4,
        unsigned* __restrict__ bkt, int* __restrict__ counts) {
    __shared__ int cnt[NCHUNK];
    if (threadIdx.x < NCHUNK) cnt[threadIdx.x] = 0;
    __syncthreads();
    const int b = blockIdx.x;
    const int q0 = (int)(((long long)b * NQ) / NBB);
    const int q1 = (int)(((long long)(b + 1) * NQ) / NBB);
    for (int q = q0 + threadIdx.x; q < q1; q += 1024) {
        const int4 d = dst4[q];
        const int4 s = src4[q];
        const int dd[4] = {d.x, d.y, d.z, d.w};
        const int ss[4] = {s.x, s.y, s.z, s.w};
#pragma unroll
        for (int j = 0; j < 4; ++j) {
            const int c = dd[j] / CHUNK;
            const int slot = atomicAdd(&cnt[c], 1);
            bkt[((size_t)c * NBB + b) * BCAP + slot] =
                ((unsigned)(dd[j] - c * CHUNK) << 17) | (unsigned)ss[j];
        }
    }
    __syncthreads();
    if (threadIdx.x < NCHUNK)
        counts[threadIdx.x * NBB + b] = cnt[threadIdx.x];
}

__global__ __launch_bounds__(1024) void scatter_bkt_kernel(
        const float* __restrict__ h,
        const unsigned* __restrict__ bkt, const int* __restrict__ counts,
        float* __restrict__ partial) {
    __shared__ float acc[CHUNK];
    const int s = blockIdx.x, c = blockIdx.y;
    for (int i = threadIdx.x; i < CHUNK; i += 1024) acc[i] = 0.0f;
    __syncthreads();
    const int lane = threadIdx.x & 63;
    const int w = threadIdx.x >> 6;
#pragma unroll
    for (int k = 0; k < 2; ++k) {
        const int b = s * GPS + w + k * 16;
        const int n = counts[c * NBB + b];
        const unsigned* bp = bkt + ((size_t)c * NBB + b) * BCAP;
        const uint4* bp4 = (const uint4*)bp;
        const int n4 = n >> 2;
        for (int q = lane; q < n4; q += 64) {
            const uint4 e = bp4[q];
            atomicAdd(&acc[e.x >> 17], h[e.x & 0x1FFFF]);
            atomicAdd(&acc[e.y >> 17], h[e.y & 0x1FFFF]);
            atomicAdd(&acc[e.z >> 17], h[e.z & 0x1FFFF]);
            atomicAdd(&acc[e.w >> 17], h[e.w & 0x1FFFF]);
        }
        const int base = n4 << 2;
        if (base + lane < n) {
            const unsigned e = bp[base + lane];
            atomicAdd(&acc[e >> 17], h[e & 0x1FFFF]);
        }
    }
    __syncthreads();
    float* outp = partial + ((size_t)c * NSLICE + s) * CHUNK;
    for (int i = threadIdx.x; i < CHUNK; i += 1024) outp[i] = acc[i];
}

__global__ __launch_bounds__(256) void reduce_mlp_kernel(
        const float* __restrict__ partial,
        const float* __restrict__ W1, const float* __restrict__ b1,
        const float* __restrict__ W2,
        float* __restrict__ sout, int n) {
    int i = blockIdx.x * blockDim.x + threadIdx.x;
    if (i >= n) return;
    const int c = i / CHUNK;
    const int idx = i - c * CHUNK;
    const float* base = partial + (size_t)c * NSLICE * CHUNK + idx;
    float a = 0.0f;
#pragma unroll
    for (int s = 0; s < NSLICE; ++s) a += base[(size_t)s * CHUNK];
    float r = 0.0f;
#pragma unroll
    for (int j = 0; j < 16; ++j)
        r = fmaf(fmaxf(fmaf(a, W1[j], b1[j]), 0.0f), W2[j], r);
    sout[i] = r;
}

__global__ __launch_bounds__(256) void reduce_final_kernel(
        const float* __restrict__ partial,
        const float* __restrict__ b2,
        float* __restrict__ out, int n) {
    int i = blockIdx.x * blockDim.x + threadIdx.x;
    if (i >= n) return;
    const int c = i / CHUNK;
    const int idx = i - c * CHUNK;
    const float* base = partial + (size_t)c * NSLICE * CHUNK + idx;
    float a = 0.0f;
#pragma unroll
    for (int s = 0; s < NSLICE; ++s) a += base[(size_t)s * CHUNK];
    out[i] = fmaxf(a + b2[0], 0.0f);
}

extern "C" void kernel_launch(void* const* d_in, const int* in_sizes, int n_in,
                              void* d_out, int out_size, void* d_ws, size_t ws_size,
                              hipStream_t stream) {
    const float* features = (const float*)d_in[0];
    const int*   src      = (const int*)d_in[1];
    const int*   dst      = (const int*)d_in[2];
    const float* W1       = (const float*)d_in[3];
    const float* b1       = (const float*)d_in[4];
    const float* W2       = (const float*)d_in[5];
    const float* b2       = (const float*)d_in[6];
    float* out = (float*)d_out;

    const size_t bkt_elems  = (size_t)NCHUNK * NBB * BCAP;       // 5.24M u32
    const size_t cnt_elems  = (size_t)NCHUNK * NBB;              // 16384 int
    const size_t part_elems = (size_t)NCHUNK * NSLICE * CHUNK;   // 1.6M f32

    unsigned* bkt  = (unsigned*)d_ws;
    int* counts    = (int*)(bkt + bkt_elems);
    float* partial = (float*)(counts + cnt_elems);
    float* sbuf    = partial + part_elems;

    const int4* src4 = (const int4*)src;
    const int4* dst4 = (const int4*)dst;

    // ---- Plan A: single cooperative dispatch ----
    {
        void* args[] = {
            (void*)&features, (void*)&src4, (void*)&dst4,
            (void*)&W1, (void*)&b1, (void*)&W2, (void*)&b2,
            (void*)&bkt, (void*)&counts, (void*)&partial, (void*)&sbuf,
            (void*)&out,
        };
        hipError_t e = hipLaunchCooperativeKernel(
            (const void*)fused_kernel, dim3(NBB), dim3(1024), args, 0, stream);
        if (e == hipSuccess) return;
    }

    // ---- Fallback: R6 5-kernel path ----
    const int nb = (NN + 255) / 256;
    bucket_kernel<<<NBB, 1024, 0, stream>>>(src4, dst4, bkt, counts);
    dim3 g(NSLICE, NCHUNK);
    scatter_bkt_kernel<<<g, 1024, 0, stream>>>(features, bkt, counts, partial);
    reduce_mlp_kernel<<<nb, 256, 0, stream>>>(partial, W1, b1, W2, sbuf, NN);
    scatter_bkt_kernel<<<g, 1024, 0, stream>>>(sbuf, bkt, counts, partial);
    reduce_final_kernel<<<nb, 256, 0, stream>>>(partial, b2, out, NN);
}